// Round 5
// baseline (1609.444 us; speedup 1.0000x reference)
//
#include <hip/hip_runtime.h>
#include <cstdint>
#include <cstddef>

// ---------------------------------------------------------------------------
// ActorNetSpiking: layer-by-layer over time; spike trains bit-packed; FC
// layers as exact-order f32 VALU GEMM with A-bits in VGPRs and B weights in
// SGPRs (scalar loads from pre-transposed Wt[k][n]) -- no LDS, no barriers.
// Arithmetic per output: k-ascending single-accumulator fma chain + bias,
// bit-identical to the validated round-0/round-4 numerics.
// ---------------------------------------------------------------------------

#define NB 4096
#define MTOT (NB * 50)

__device__ __forceinline__ void neuron_update(float syn, float& u, float& v, float& s) {
    u = u * 0.5f + syn;
    v = v * 0.75f * (1.0f - s) + u;
    s = (v > 0.5f) ? 1.0f : 0.0f;
}

// ------------------------- conv1: (B,1,360) -> (B,5,178) --------------------
__global__ __launch_bounds__(192) void conv1_kernel(
    const float* __restrict__ x, const float* __restrict__ w1,
    const float* __restrict__ b1, unsigned long long* __restrict__ S1)
{
    __shared__ float xl[9000];
    const int tid = threadIdx.x;
    const int b = blockIdx.x;
    const int j = tid;
    const int lbase = (j < 178) ? 2 * j : 354;

    float wr[25], br[5];
#pragma unroll
    for (int q = 0; q < 25; ++q) wr[q] = w1[q];
#pragma unroll
    for (int o = 0; o < 5; ++o) br[o] = b1[o];

    float u[5], v[5], s[5];
#pragma unroll
    for (int o = 0; o < 5; ++o) { u[o] = 0.f; v[o] = 0.f; s[o] = 0.f; }

    const float* xb = x + (size_t)b * 18000;
    for (int half = 0; half < 2; ++half) {
        const int t0 = half * 25;
        __syncthreads();
        for (int e = tid; e < 9000; e += 192)
            xl[e] = xb[(e / 25) * 50 + t0 + (e % 25)];
        __syncthreads();
        for (int dt = 0; dt < 25; ++dt) {
            const int t = t0 + dt;
            float xv[5];
#pragma unroll
            for (int k = 0; k < 5; ++k) xv[k] = xl[(lbase + k) * 25 + dt];
#pragma unroll
            for (int o = 0; o < 5; ++o) {
                float syn = 0.f;
#pragma unroll
                for (int k = 0; k < 5; ++k) syn += wr[o * 5 + k] * xv[k];
                syn += br[o];
                neuron_update(syn, u[o], v[o], s[o]);
                unsigned long long m = __ballot(j < 178 && s[o] > 0.5f);
                if ((tid & 63) == 0)
                    S1[(((size_t)b * 50 + t) * 5 + o) * 3 + (tid >> 6)] = m;
            }
        }
    }
}

// ------------------------- conv2: (B,5,178) -> (B,5,87) ---------------------
__global__ __launch_bounds__(128) void conv2_kernel(
    const unsigned int* __restrict__ S1, const float* __restrict__ w2,
    const float* __restrict__ b2, unsigned int* __restrict__ S2)
{
    __shared__ unsigned int s1l[1501];
    const int tid = threadIdx.x;
    const int b = blockIdx.x;

    float wr[125], br[5];
#pragma unroll
    for (int q = 0; q < 125; ++q) wr[q] = w2[q];
#pragma unroll
    for (int o = 0; o < 5; ++o) br[o] = b2[o];

    const unsigned int* src = S1 + (size_t)b * 1500;
    for (int e = tid; e < 1500; e += 128) s1l[e] = src[e];
    __syncthreads();

    const int p = (tid < 87) ? 2 * tid : 172;
    const int pw = p >> 5, ps = p & 31;

    float u[5], v[5], s[5];
#pragma unroll
    for (int o = 0; o < 5; ++o) { u[o] = 0.f; v[o] = 0.f; s[o] = 0.f; }

    for (int t = 0; t < 50; ++t) {
        float xv[25];
#pragma unroll
        for (int ci = 0; ci < 5; ++ci) {
            const int base = (t * 5 + ci) * 6 + pw;
            unsigned long long bits =
                ((((unsigned long long)s1l[base + 1]) << 32) | (unsigned long long)s1l[base]) >> ps;
#pragma unroll
            for (int k = 0; k < 5; ++k)
                xv[ci * 5 + k] = ((bits >> k) & 1ULL) ? 1.0f : 0.0f;
        }
#pragma unroll
        for (int o = 0; o < 5; ++o) {
            float syn = 0.f;
#pragma unroll
            for (int q = 0; q < 25; ++q) syn += wr[o * 25 + q] * xv[q];
            syn += br[o];
            neuron_update(syn, u[o], v[o], s[o]);
            unsigned long long m = __ballot(tid < 87 && s[o] > 0.5f);
            const size_t outb = (((size_t)b * 50 + t) * 5 + o) * 3;
            if (tid == 0) {
                S2[outb]     = (unsigned int)m;
                S2[outb + 1] = (unsigned int)(m >> 32);
            }
            if (tid == 64) S2[outb + 2] = (unsigned int)m;
        }
    }
}

// ------------------------- conv3: (B,5,87) -> transposed 216-bit rows -------
// Row m = b*50+t has bits k=0..209 (conv3 spikes, k=o*42+j), 210..215 (normal
// spikes). Stored TRANSPOSED: ST0[w*MTOT + m] = word w (k = 32w..32w+31).
__global__ __launch_bounds__(64) void conv3_kernel(
    const unsigned int* __restrict__ S2, const float* __restrict__ w3,
    const float* __restrict__ b3, const float* __restrict__ normal,
    unsigned int* __restrict__ ST0)
{
    __shared__ unsigned int s2l[751];
    const int tid = threadIdx.x;
    const int b = blockIdx.x;

    float wr[125], br[5];
#pragma unroll
    for (int q = 0; q < 125; ++q) wr[q] = w3[q];
#pragma unroll
    for (int o = 0; o < 5; ++o) br[o] = b3[o];

    const unsigned int* src = S2 + (size_t)b * 750;
    for (int e = tid; e < 750; e += 64) s2l[e] = src[e];
    __syncthreads();

    const int p = (tid < 42) ? 2 * tid : 82;
    const int pw = p >> 5, ps = p & 31;

    float u[5], v[5], s[5];
#pragma unroll
    for (int o = 0; o < 5; ++o) { u[o] = 0.f; v[o] = 0.f; s[o] = 0.f; }

    for (int t = 0; t < 50; ++t) {
        float xv[25];
#pragma unroll
        for (int ci = 0; ci < 5; ++ci) {
            const int base = (t * 5 + ci) * 3 + pw;
            unsigned long long bits =
                ((((unsigned long long)s2l[base + 1]) << 32) | (unsigned long long)s2l[base]) >> ps;
#pragma unroll
            for (int k = 0; k < 5; ++k)
                xv[ci * 5 + k] = ((bits >> k) & 1ULL) ? 1.0f : 0.0f;
        }
        unsigned long long m[5];
#pragma unroll
        for (int o = 0; o < 5; ++o) {
            float syn = 0.f;
#pragma unroll
            for (int q = 0; q < 25; ++q) syn += wr[o * 25 + q] * xv[q];
            syn += br[o];
            neuron_update(syn, u[o], v[o], s[o]);
            m[o] = __ballot(tid < 42 && s[o] > 0.5f);
        }
        const unsigned long long nm =
            __ballot(tid < 6 && normal[((size_t)b * 6 + tid) * 50 + t] > 0.5f);
        if (tid == 0) {
            const unsigned long long r0 = m[0] | (m[1] << 42);
            const unsigned long long r1 = (m[1] >> 22) | (m[2] << 20) | (m[3] << 62);
            const unsigned long long r2 = (m[3] >> 2) | (m[4] << 40);
            const unsigned long long r3 = (m[4] >> 24) | (nm << 18);
            const size_t mrow = (size_t)b * 50 + t;
            ST0[0 * (size_t)MTOT + mrow] = (unsigned int)r0;
            ST0[1 * (size_t)MTOT + mrow] = (unsigned int)(r0 >> 32);
            ST0[2 * (size_t)MTOT + mrow] = (unsigned int)r1;
            ST0[3 * (size_t)MTOT + mrow] = (unsigned int)(r1 >> 32);
            ST0[4 * (size_t)MTOT + mrow] = (unsigned int)r2;
            ST0[5 * (size_t)MTOT + mrow] = (unsigned int)(r2 >> 32);
            ST0[6 * (size_t)MTOT + mrow] = (unsigned int)r3;
        }
    }
}

// ------------------------- weight transpose prep -----------------------------
// Wt[k][n] = W[n][k] for k < KREAL, else 0. Exact copy, no rounding.
__global__ __launch_bounds__(256) void transpose_w_kernel(
    const float* __restrict__ W, float* __restrict__ Wt, int N, int KREAL, int KPAD)
{
    const int idx = blockIdx.x * 256 + threadIdx.x;
    if (idx >= KPAD * N) return;
    const int k = idx / N, n = idx % N;
    Wt[idx] = (k < KREAL) ? W[(size_t)n * KREAL + k] : 0.f;
}

// ------------------------- exact-order bit GEMM (no LDS) --------------------
// syn[m][n] = (sum_{k ascending} bit(m,k)*Wt[k][n]) + bias[n].
// lane = m (coalesced A-bit loads from bitsT[w][m]); n-tile of 32 from
// blockIdx.y (wave-uniform -> Wt reads become s_load into SGPRs).
__global__ __launch_bounds__(256) void sgemm_bits_kernel(
    const uint32_t* __restrict__ bitsT,   // [8][MTOT] u32, word-major
    const float* __restrict__ Wt,         // [KPAD][Ntot]
    const float* __restrict__ bias,       // (Ntot,)
    float* __restrict__ syn,              // [Mchunk][Ntot]
    int Ntot, int KT, int row0)
{
    const int tid = threadIdx.x;
    const int mloc = blockIdx.x * 256 + tid;
    const int mg = row0 + mloc;
    const int nbase = blockIdx.y * 32;

    // whole A panel for this thread: KT u32 words (coalesced per word-plane)
    uint32_t aw[8];
#pragma unroll
    for (int w = 0; w < 8; ++w)
        aw[w] = (w < KT) ? bitsT[(size_t)w * MTOT + mg] : 0u;

    float acc[32];
#pragma unroll
    for (int j = 0; j < 32; ++j) acc[j] = 0.f;

    const float* wt = Wt + nbase;
    for (int kt = 0; kt < KT; ++kt) {
        const uint32_t abit = aw[kt];
        const float* wk = wt + (size_t)(kt * 32) * Ntot;
#pragma unroll
        for (int kk = 0; kk < 32; ++kk) {
            const float a = (float)((abit >> kk) & 1u);   // bfe + cvt
            const float* wr = wk + (size_t)kk * Ntot;     // uniform address
#pragma unroll
            for (int j = 0; j < 32; ++j)
                acc[j] = fmaf(a, wr[j], acc[j]);          // scalar B operand
        }
    }

    // epilogue: bias-last (exact), vectorized contiguous store
    float* so = syn + (size_t)mloc * Ntot + nbase;
    const float* bs = bias + nbase;
#pragma unroll
    for (int q = 0; q < 8; ++q) {
        float4 ov;
        ov.x = acc[q * 4 + 0] + bs[q * 4 + 0];
        ov.y = acc[q * 4 + 1] + bs[q * 4 + 1];
        ov.z = acc[q * 4 + 2] + bs[q * 4 + 2];
        ov.w = acc[q * 4 + 3] + bs[q * 4 + 3];
        *reinterpret_cast<float4*>(so + q * 4) = ov;
    }
}

// ------------------------- FC scan, transposed bit output (N=256) -----------
__global__ __launch_bounds__(256) void fc_scanT_kernel(
    const float* __restrict__ syn,        // [chunk*50][256]
    uint32_t* __restrict__ SFT,           // [8][MTOT] u32
    int b0)
{
    const int tid = threadIdx.x;
    const int lane = tid & 63;
    const int ob = tid >> 6;              // 0..3 (64-neuron group)
    const int bl = blockIdx.x;            // local batch element
    const int o = ob * 64 + lane;

    float u = 0.f, v = 0.f, s = 0.f;
    for (int t = 0; t < 50; ++t) {
        const float sv = syn[((size_t)bl * 50 + t) * 256 + o];
        neuron_update(sv, u, v, s);
        const unsigned long long m = __ballot(s > 0.5f);
        if (lane == 0) {
            const size_t row = (size_t)(b0 + bl) * 50 + t;
            SFT[(size_t)(2 * ob) * MTOT + row]     = (uint32_t)m;
            SFT[(size_t)(2 * ob + 1) * MTOT + row] = (uint32_t)(m >> 32);
        }
    }
}

// ------------------------- FC scan, row-major u64 output (N=128) ------------
__global__ __launch_bounds__(256) void fc_scan128_kernel(
    const float* __restrict__ syn,             // [chunk*50][128]
    unsigned long long* __restrict__ SF,       // [MTOT][2] u64
    int b0)
{
    const int tid = threadIdx.x;
    const int wid = blockIdx.x * 4 + (tid >> 6);
    const int lane = tid & 63;
    const int bl = wid >> 1;
    const int ob = wid & 1;
    const int o = ob * 64 + lane;

    float u = 0.f, v = 0.f, s = 0.f;
    for (int t = 0; t < 50; ++t) {
        const float sv = syn[((size_t)bl * 50 + t) * 128 + o];
        neuron_update(sv, u, v, s);
        const unsigned long long m = __ballot(s > 0.5f);
        if (lane == 0) SF[((size_t)(b0 + bl) * 50 + t) * 2 + ob] = m;
    }
}

// ------------------------- fc4 GEMM (N=2, K=128) ----------------------------
__global__ __launch_bounds__(256) void fc4_gemm_kernel(
    const unsigned long long* __restrict__ SF3, const float* __restrict__ W,
    const float* __restrict__ bias, float* __restrict__ syn4)
{
    const int m = blockIdx.x * 256 + threadIdx.x;
    const unsigned long long w0 = SF3[(size_t)m * 2];
    const unsigned long long w1 = SF3[(size_t)m * 2 + 1];
    float a0 = 0.f, a1 = 0.f;
#pragma unroll
    for (int i = 0; i < 64; ++i) {
        const float bit = ((w0 >> i) & 1ULL) ? 1.f : 0.f;
        a0 = fmaf(bit, W[i], a0);
        a1 = fmaf(bit, W[128 + i], a1);
    }
#pragma unroll
    for (int i = 0; i < 64; ++i) {
        const float bit = ((w1 >> i) & 1ULL) ? 1.f : 0.f;
        a0 = fmaf(bit, W[64 + i], a0);
        a1 = fmaf(bit, W[192 + i], a1);
    }
    syn4[(size_t)m * 2]     = a0 + bias[0];
    syn4[(size_t)m * 2 + 1] = a1 + bias[1];
}

__global__ __launch_bounds__(64) void fc4_scan_kernel(
    const float* __restrict__ syn4, float* __restrict__ out)
{
    const int b = blockIdx.x * 64 + threadIdx.x;
    float u0 = 0.f, v0 = 0.f, s0 = 0.f, acc0 = 0.f;
    float u1 = 0.f, v1 = 0.f, s1 = 0.f, acc1 = 0.f;
    for (int t = 0; t < 50; ++t) {
        const float x0 = syn4[((size_t)b * 50 + t) * 2];
        const float x1 = syn4[((size_t)b * 50 + t) * 2 + 1];
        neuron_update(x0, u0, v0, s0); acc0 += s0;
        neuron_update(x1, u1, v1, s1); acc1 += s1;
    }
    out[b * 2]     = acc0 / 50.0f;
    out[b * 2 + 1] = acc1 / 50.0f;
}

// ---------------------------------------------------------------------------
extern "C" void kernel_launch(void* const* d_in, const int* in_sizes, int n_in,
                              void* d_out, int out_size, void* d_ws, size_t ws_size,
                              hipStream_t stream) {
    (void)in_sizes; (void)n_in; (void)out_size;
    const float* normal = (const float*)d_in[0];
    const float* xscan  = (const float*)d_in[1];
    const float* w1  = (const float*)d_in[3];
    const float* b1  = (const float*)d_in[4];
    const float* w2  = (const float*)d_in[5];
    const float* b2  = (const float*)d_in[6];
    const float* w3  = (const float*)d_in[7];
    const float* b3  = (const float*)d_in[8];
    const float* fw1 = (const float*)d_in[9];
    const float* fb1 = (const float*)d_in[10];
    const float* fw2 = (const float*)d_in[11];
    const float* fb2 = (const float*)d_in[12];
    const float* fw3 = (const float*)d_in[13];
    const float* fb3 = (const float*)d_in[14];
    const float* fw4 = (const float*)d_in[15];
    const float* fb4 = (const float*)d_in[16];
    float* out = (float*)d_out;

    char* wp = (char*)d_ws;
    size_t off = 0;
    auto take = [&](size_t bytes) -> void* {
        void* p = wp + off;
        off += (bytes + 255) & ~(size_t)255;
        return p;
    };
    float* Wt1 = (float*)take((size_t)224 * 256 * 4);
    float* Wt2 = (float*)take((size_t)256 * 256 * 4);
    float* Wt3 = (float*)take((size_t)256 * 128 * 4);
    unsigned long long* S1  = (unsigned long long*)take((size_t)NB * 50 * 15 * 8);
    unsigned int*       S2  = (unsigned int*)take((size_t)NB * 50 * 15 * 4);
    uint32_t* ST0 = (uint32_t*)take((size_t)8 * MTOT * 4);
    uint32_t* ST1 = (uint32_t*)take((size_t)8 * MTOT * 4);
    uint32_t* ST2 = (uint32_t*)take((size_t)8 * MTOT * 4);
    unsigned long long* SF3 = (unsigned long long*)take((size_t)MTOT * 2 * 8);
    float*              syn4 = (float*)take((size_t)MTOT * 2 * 4);

    int chunk = NB;
    while (chunk > 128 && off + (size_t)chunk * 50 * 256 * 4 > ws_size) chunk >>= 1;
    float* syn = (float*)take((size_t)chunk * 50 * 256 * 4);

    transpose_w_kernel<<<(224 * 256 + 255) / 256, 256, 0, stream>>>(fw1, Wt1, 256, 216, 224);
    transpose_w_kernel<<<(256 * 256 + 255) / 256, 256, 0, stream>>>(fw2, Wt2, 256, 256, 256);
    transpose_w_kernel<<<(256 * 128 + 255) / 256, 256, 0, stream>>>(fw3, Wt3, 128, 256, 256);

    conv1_kernel<<<NB, 192, 0, stream>>>(xscan, w1, b1, S1);
    conv2_kernel<<<NB, 128, 0, stream>>>((const unsigned int*)S1, w2, b2, S2);
    conv3_kernel<<<NB, 64, 0, stream>>>(S2, w3, b3, normal, ST0);

    for (int b0 = 0; b0 < NB; b0 += chunk) {
        sgemm_bits_kernel<<<dim3(chunk * 50 / 256, 8), 256, 0, stream>>>(
            ST0, Wt1, fb1, syn, 256, 7, b0 * 50);
        fc_scanT_kernel<<<chunk, 256, 0, stream>>>(syn, ST1, b0);
    }
    for (int b0 = 0; b0 < NB; b0 += chunk) {
        sgemm_bits_kernel<<<dim3(chunk * 50 / 256, 8), 256, 0, stream>>>(
            ST1, Wt2, fb2, syn, 256, 8, b0 * 50);
        fc_scanT_kernel<<<chunk, 256, 0, stream>>>(syn, ST2, b0);
    }
    for (int b0 = 0; b0 < NB; b0 += chunk) {
        sgemm_bits_kernel<<<dim3(chunk * 50 / 256, 4), 256, 0, stream>>>(
            ST2, Wt3, fb3, syn, 128, 8, b0 * 50);
        fc_scan128_kernel<<<chunk / 2, 256, 0, stream>>>(syn, SF3, b0);
    }
    fc4_gemm_kernel<<<MTOT / 256, 256, 0, stream>>>(SF3, fw4, fb4, syn4);
    fc4_scan_kernel<<<NB / 64, 64, 0, stream>>>(syn4, out);
}